// Round 1
// baseline (8044.604 us; speedup 1.0000x reference)
//
#include <hip/hip_runtime.h>

#define LRELU(v) ((v) >= 0.f ? (v) : 0.2f * (v))

constexpr int Nn = 50000;
constexpr int Ee = 800000;
constexpr int Dd = 128;
constexpr int Hh = 256;
constexpr int Gg = 128;
constexpr int Oo = 10;

// ---------------------------------------------------------------------------
// Edge kernel: msg = ReLU(x[src] + edge_attr @ We + be); atomicAdd into agg[dst]
// ---------------------------------------------------------------------------
template<int DIN>
__global__ __launch_bounds__(256) void edge_kernel(
    const float* __restrict__ x, const int* __restrict__ src, const int* __restrict__ dst,
    const float* __restrict__ ea, const float* __restrict__ We, const float* __restrict__ be,
    float* __restrict__ agg)
{
  constexpr int TPE = DIN / 4;   // threads per edge (float4 per thread)
  constexpr int EPB = 256 / TPE; // edges per block
  const int e = blockIdx.x * EPB + threadIdx.x / TPE;
  if (e >= Ee) return;
  const int fo = (threadIdx.x % TPE) * 4;
  const int s = src[e], d = dst[e];
  const float a0 = ea[e * 3 + 0], a1 = ea[e * 3 + 1], a2 = ea[e * 3 + 2];
  const float4 xv = *reinterpret_cast<const float4*>(x + (size_t)s * DIN + fo);
  const float4 w0 = *reinterpret_cast<const float4*>(We + 0 * DIN + fo);
  const float4 w1 = *reinterpret_cast<const float4*>(We + 1 * DIN + fo);
  const float4 w2 = *reinterpret_cast<const float4*>(We + 2 * DIN + fo);
  const float4 bv = *reinterpret_cast<const float4*>(be + fo);
  float* out = agg + (size_t)d * DIN + fo;
  float m;
  m = xv.x + a0 * w0.x + a1 * w1.x + a2 * w2.x + bv.x; atomicAdd(out + 0, fmaxf(m, 0.f));
  m = xv.y + a0 * w0.y + a1 * w1.y + a2 * w2.y + bv.y; atomicAdd(out + 1, fmaxf(m, 0.f));
  m = xv.z + a0 * w0.z + a1 * w1.z + a2 * w2.z + bv.z; atomicAdd(out + 2, fmaxf(m, 0.f));
  m = xv.w + a0 * w0.w + a1 * w1.w + a2 * w2.w + bv.w; atomicAdd(out + 3, fmaxf(m, 0.f));
}

// ---------------------------------------------------------------------------
// Node GEMM: C[N,256] = epilogue( (A (+A2)) @ W + bias ), W is [DIN,256]
// DOBN: BN(eval) + leaky ; else bias + leaky
// 64x64 tile, BK=16, 256 threads, 4x4 per thread.
// ---------------------------------------------------------------------------
template<int DIN, bool ADD2, bool DOBN>
__global__ __launch_bounds__(256) void node_gemm(
    const float* __restrict__ A, const float* __restrict__ A2,
    const float* __restrict__ W, const float* __restrict__ bias,
    const float* __restrict__ gamma, const float* __restrict__ beta,
    const float* __restrict__ mu, const float* __restrict__ var,
    float* __restrict__ C)
{
  constexpr int BM = 64, BNc = 64, BK = 16;
  __shared__ float As[BK][BM + 1];
  __shared__ float Ws[BK][BNc + 1];
  const int r0 = blockIdx.y * BM;
  const int c0 = blockIdx.x * BNc;
  const int t  = threadIdx.x;
  const int tx = t & 15, ty = t >> 4;
  float acc[4][4] = {};

  for (int k0 = 0; k0 < DIN; k0 += BK) {
    // A tile: 64 rows x 16 k
    #pragma unroll
    for (int i = 0; i < 4; i++) {
      const int row = (t >> 4) + i * 16;
      const int kk  = t & 15;
      const int gr  = r0 + row;
      float v = 0.f;
      if (gr < Nn) {
        const size_t off = (size_t)gr * DIN + k0 + kk;
        v = A[off];
        if (ADD2) v += A2[off];
      }
      As[kk][row] = v;
    }
    // W tile: 16 k x 64 cols
    #pragma unroll
    for (int i = 0; i < 4; i++) {
      const int kk = (t >> 6) + i * 4;
      const int cc = t & 63;
      Ws[kk][cc] = W[(size_t)(k0 + kk) * Hh + c0 + cc];
    }
    __syncthreads();
    #pragma unroll
    for (int kk = 0; kk < BK; kk++) {
      float a[4], b[4];
      #pragma unroll
      for (int i = 0; i < 4; i++) a[i] = As[kk][ty * 4 + i];
      #pragma unroll
      for (int j = 0; j < 4; j++) b[j] = Ws[kk][tx * 4 + j];
      #pragma unroll
      for (int i = 0; i < 4; i++)
        #pragma unroll
        for (int j = 0; j < 4; j++)
          acc[i][j] = fmaf(a[i], b[j], acc[i][j]);
    }
    __syncthreads();
  }

  #pragma unroll
  for (int i = 0; i < 4; i++) {
    const int row = r0 + ty * 4 + i;
    if (row >= Nn) continue;
    #pragma unroll
    for (int j = 0; j < 4; j++) {
      const int col = c0 + tx * 4 + j;
      float v = acc[i][j] + bias[col];
      if (DOBN)
        v = gamma[col] * (v - mu[col]) * rsqrtf(var[col] + 1e-5f) + beta[col];
      v = LRELU(v);
      C[(size_t)row * Hh + col] = v;
    }
  }
}

// ---------------------------------------------------------------------------
// Pool: segment_sum over sorted batch into pooled[G, 768] at column offset
// Each block: 16 consecutive nodes, 256 threads = columns; local accumulate runs.
// ---------------------------------------------------------------------------
__global__ __launch_bounds__(256) void pool_kernel(
    const float* __restrict__ xl, const int* __restrict__ batch,
    float* __restrict__ pooled, int layer)
{
  constexpr int NPB = 16;
  const int n0 = blockIdx.x * NPB;
  const int c  = threadIdx.x;
  if (n0 >= Nn) return;
  float acc = 0.f;
  int curb = batch[n0];
  for (int i = 0; i < NPB; i++) {
    const int n = n0 + i;
    if (n >= Nn) break;
    const int b = batch[n];
    if (b != curb) {
      atomicAdd(pooled + (size_t)curb * 768 + layer * 256 + c, acc);
      acc = 0.f;
      curb = b;
    }
    acc += xl[(size_t)n * 256 + c];
  }
  atomicAdd(pooled + (size_t)curb * 768 + layer * 256 + c, acc);
}

// ---------------------------------------------------------------------------
// MLP: out[G, NC] = act( in[G,K] @ W[K,NC] + b ), act = double-leaky or none
// ---------------------------------------------------------------------------
__global__ __launch_bounds__(256) void mlp_kernel(
    const float* __restrict__ in, const float* __restrict__ W,
    const float* __restrict__ b, float* __restrict__ out,
    int K, int NC, int act)
{
  const int idx = blockIdx.x * blockDim.x + threadIdx.x;
  if (idx >= Gg * NC) return;
  const int r = idx / NC, c = idx % NC;
  float acc = b[c];
  for (int k = 0; k < K; k++) acc = fmaf(in[r * K + k], W[k * NC + c], acc);
  if (act) { acc = LRELU(acc); acc = LRELU(acc); }
  out[idx] = acc;
}

// ---------------------------------------------------------------------------
extern "C" void kernel_launch(void* const* d_in, const int* in_sizes, int n_in,
                              void* d_out, int out_size, void* d_ws, size_t ws_size,
                              hipStream_t stream)
{
  const float* x     = (const float*)d_in[0];
  const int*   ei    = (const int*)d_in[1];
  const float* ea    = (const float*)d_in[2];
  const int*   batch = (const int*)d_in[3];
  const int* src = ei;
  const int* dst = ei + Ee;

  const float *We[3], *be_[3], *W1[3], *b1[3], *g_[3], *bt_[3], *mu_[3], *var_[3], *W2[3], *b2[3];
  for (int l = 0; l < 3; l++) {
    const int base = 4 + l * 10;
    We[l]  = (const float*)d_in[base + 0];
    be_[l] = (const float*)d_in[base + 1];
    W1[l]  = (const float*)d_in[base + 2];
    b1[l]  = (const float*)d_in[base + 3];
    g_[l]  = (const float*)d_in[base + 4];
    bt_[l] = (const float*)d_in[base + 5];
    mu_[l] = (const float*)d_in[base + 6];
    var_[l]= (const float*)d_in[base + 7];
    W2[l]  = (const float*)d_in[base + 8];
    b2[l]  = (const float*)d_in[base + 9];
  }
  const float *Wm[4], *bm[4];
  for (int i = 0; i < 4; i++) {
    Wm[i] = (const float*)d_in[34 + 2 * i];
    bm[i] = (const float*)d_in[35 + 2 * i];
  }

  float* agg    = (float*)d_ws;                      // N*256
  float* tmp    = agg    + (size_t)Nn * Hh;          // N*256
  float* bufA   = tmp    + (size_t)Nn * Hh;          // N*256
  float* bufB   = bufA   + (size_t)Nn * Hh;          // N*256
  float* pooled = bufB   + (size_t)Nn * Hh;          // G*768
  float* h1     = pooled + (size_t)Gg * 768;         // G*200
  float* h2     = h1     + (size_t)Gg * 200;         // G*200
  float* outf   = (float*)d_out;

  const dim3 gemmGrid(Hh / 64, (Nn + 63) / 64);
  const int poolGrid = (Nn + 15) / 16;

  hipMemsetAsync(pooled, 0, (size_t)Gg * 768 * sizeof(float), stream);

  // ---- layer 1 (din = 128) ----
  hipMemsetAsync(agg, 0, (size_t)Nn * Dd * sizeof(float), stream);
  edge_kernel<128><<<(Ee + 1) / 2, 256, 0, stream>>>(x, src, dst, ea, We[0], be_[0], agg);
  node_gemm<128, true, true><<<gemmGrid, 256, 0, stream>>>(
      x, agg, W1[0], b1[0], g_[0], bt_[0], mu_[0], var_[0], tmp);
  node_gemm<256, false, false><<<gemmGrid, 256, 0, stream>>>(
      tmp, nullptr, W2[0], b2[0], nullptr, nullptr, nullptr, nullptr, bufA);
  pool_kernel<<<poolGrid, 256, 0, stream>>>(bufA, batch, pooled, 0);

  // ---- layer 2 (din = 256) ----
  hipMemsetAsync(agg, 0, (size_t)Nn * Hh * sizeof(float), stream);
  edge_kernel<256><<<(Ee + 3) / 4, 256, 0, stream>>>(bufA, src, dst, ea, We[1], be_[1], agg);
  node_gemm<256, true, true><<<gemmGrid, 256, 0, stream>>>(
      bufA, agg, W1[1], b1[1], g_[1], bt_[1], mu_[1], var_[1], tmp);
  node_gemm<256, false, false><<<gemmGrid, 256, 0, stream>>>(
      tmp, nullptr, W2[1], b2[1], nullptr, nullptr, nullptr, nullptr, bufB);
  pool_kernel<<<poolGrid, 256, 0, stream>>>(bufB, batch, pooled, 1);

  // ---- layer 3 (din = 256) ----
  hipMemsetAsync(agg, 0, (size_t)Nn * Hh * sizeof(float), stream);
  edge_kernel<256><<<(Ee + 3) / 4, 256, 0, stream>>>(bufB, src, dst, ea, We[2], be_[2], agg);
  node_gemm<256, true, true><<<gemmGrid, 256, 0, stream>>>(
      bufB, agg, W1[2], b1[2], g_[2], bt_[2], mu_[2], var_[2], tmp);
  node_gemm<256, false, false><<<gemmGrid, 256, 0, stream>>>(
      tmp, nullptr, W2[2], b2[2], nullptr, nullptr, nullptr, nullptr, bufA);
  pool_kernel<<<poolGrid, 256, 0, stream>>>(bufA, batch, pooled, 2);

  // ---- MLP head ----
  mlp_kernel<<<(Gg * 200 + 255) / 256, 256, 0, stream>>>(pooled, Wm[0], bm[0], h1, 768, 200, 1);
  mlp_kernel<<<(Gg * 200 + 255) / 256, 256, 0, stream>>>(h1, Wm[1], bm[1], h2, 200, 200, 1);
  mlp_kernel<<<(Gg * 200 + 255) / 256, 256, 0, stream>>>(h2, Wm[2], bm[2], h1, 200, 200, 1);
  mlp_kernel<<<(Gg * Oo + 255) / 256, 256, 0, stream>>>(h1, Wm[3], bm[3], outf, 200, 10, 0);
}

// Round 2
// 1803.377 us; speedup vs baseline: 4.4609x; 4.4609x over previous
//
#include <hip/hip_runtime.h>

#define LRELU(v) ((v) >= 0.f ? (v) : 0.2f * (v))

constexpr int Nn = 50000;
constexpr int Ee = 800000;
constexpr int Dd = 128;
constexpr int Hh = 256;
constexpr int Gg = 128;
constexpr int Oo = 10;

// ---------------------------------------------------------------------------
// CSR build: histogram by dst, exclusive scan, fill (edge ids + src cache)
// ---------------------------------------------------------------------------
__global__ __launch_bounds__(256) void hist_kernel(
    const int* __restrict__ dst, int* __restrict__ deg)
{
  const int e = blockIdx.x * 256 + threadIdx.x;
  if (e < Ee) atomicAdd(&deg[dst[e]], 1);
}

// single-block exclusive scan of deg[0..n) -> row_ptr & cursor; row_ptr[n]=total
__global__ __launch_bounds__(1024) void scan_kernel(
    const int* __restrict__ deg, int* __restrict__ row_ptr,
    int* __restrict__ cursor, int n)
{
  __shared__ int sdata[1024];
  __shared__ int carry;
  const int tid = threadIdx.x;
  if (tid == 0) carry = 0;
  __syncthreads();
  for (int base = 0; base < n; base += 1024) {
    const int i = base + tid;
    const int v = (i < n) ? deg[i] : 0;
    sdata[tid] = v;
    __syncthreads();
    #pragma unroll
    for (int off = 1; off < 1024; off <<= 1) {
      const int t = (tid >= off) ? sdata[tid - off] : 0;
      __syncthreads();
      sdata[tid] += t;
      __syncthreads();
    }
    const int excl = sdata[tid] - v + carry;
    if (i < n) { row_ptr[i] = excl; cursor[i] = excl; }
    __syncthreads();
    if (tid == 1023) carry += sdata[1023];
    __syncthreads();
  }
  if (tid == 0) row_ptr[n] = carry;
}

__global__ __launch_bounds__(256) void fill_kernel(
    const int* __restrict__ src, const int* __restrict__ dst,
    int* __restrict__ cursor, int* __restrict__ csr_src, int* __restrict__ csr_eid)
{
  const int e = blockIdx.x * 256 + threadIdx.x;
  if (e >= Ee) return;
  const int pos = atomicAdd(&cursor[dst[e]], 1);
  csr_src[pos] = src[e];
  csr_eid[pos] = e;
}

// ---------------------------------------------------------------------------
// Gather aggregation: one wave per node; agg[n] = sum_e ReLU(x[src_e] + ea_e@We + be)
// ---------------------------------------------------------------------------
template<int DIN>
__global__ __launch_bounds__(256) void agg_gather(
    const float* __restrict__ x, const float* __restrict__ ea,
    const float* __restrict__ We, const float* __restrict__ be,
    const int* __restrict__ row_ptr, const int* __restrict__ csr_src,
    const int* __restrict__ csr_eid, float* __restrict__ agg)
{
  constexpr int FPL = DIN / 64;  // floats per lane: 2 (DIN=128) or 4 (DIN=256)
  const int wv   = threadIdx.x >> 6;
  const int lane = threadIdx.x & 63;
  const int n = blockIdx.x * 4 + wv;
  if (n >= Nn) return;
  const int fo = lane * FPL;

  float w0[FPL], w1[FPL], w2[FPL], bb[FPL], acc[FPL];
  #pragma unroll
  for (int j = 0; j < FPL; j++) {
    w0[j] = We[0 * DIN + fo + j];
    w1[j] = We[1 * DIN + fo + j];
    w2[j] = We[2 * DIN + fo + j];
    bb[j] = be[fo + j];
    acc[j] = 0.f;
  }

  const int beg = row_ptr[n], end = row_ptr[n + 1];
  for (int i = beg; i < end; i++) {
    const int s = csr_src[i];
    const int e = csr_eid[i];
    const float a0 = ea[3 * e + 0], a1 = ea[3 * e + 1], a2 = ea[3 * e + 2];
    float xv[FPL];
    if constexpr (FPL == 4) {
      const float4 v = *reinterpret_cast<const float4*>(x + (size_t)s * DIN + fo);
      xv[0] = v.x; xv[1] = v.y; xv[2] = v.z; xv[3] = v.w;
    } else {
      const float2 v = *reinterpret_cast<const float2*>(x + (size_t)s * DIN + fo);
      xv[0] = v.x; xv[1] = v.y;
    }
    #pragma unroll
    for (int j = 0; j < FPL; j++) {
      const float m = xv[j] + a0 * w0[j] + a1 * w1[j] + a2 * w2[j] + bb[j];
      acc[j] += fmaxf(m, 0.f);
    }
  }

  if constexpr (FPL == 4)
    *reinterpret_cast<float4*>(agg + (size_t)n * DIN + fo) =
        make_float4(acc[0], acc[1], acc[2], acc[3]);
  else
    *reinterpret_cast<float2*>(agg + (size_t)n * DIN + fo) =
        make_float2(acc[0], acc[1]);
}

// ---------------------------------------------------------------------------
// Node GEMM: C[N,256] = epilogue( (A (+A2)) @ W + bias ), W is [DIN,256]
// ---------------------------------------------------------------------------
template<int DIN, bool ADD2, bool DOBN>
__global__ __launch_bounds__(256) void node_gemm(
    const float* __restrict__ A, const float* __restrict__ A2,
    const float* __restrict__ W, const float* __restrict__ bias,
    const float* __restrict__ gamma, const float* __restrict__ beta,
    const float* __restrict__ mu, const float* __restrict__ var,
    float* __restrict__ C)
{
  constexpr int BM = 64, BNc = 64, BK = 16;
  __shared__ float As[BK][BM + 1];
  __shared__ float Ws[BK][BNc + 1];
  const int r0 = blockIdx.y * BM;
  const int c0 = blockIdx.x * BNc;
  const int t  = threadIdx.x;
  const int tx = t & 15, ty = t >> 4;
  float acc[4][4] = {};

  for (int k0 = 0; k0 < DIN; k0 += BK) {
    #pragma unroll
    for (int i = 0; i < 4; i++) {
      const int row = (t >> 4) + i * 16;
      const int kk  = t & 15;
      const int gr  = r0 + row;
      float v = 0.f;
      if (gr < Nn) {
        const size_t off = (size_t)gr * DIN + k0 + kk;
        v = A[off];
        if (ADD2) v += A2[off];
      }
      As[kk][row] = v;
    }
    #pragma unroll
    for (int i = 0; i < 4; i++) {
      const int kk = (t >> 6) + i * 4;
      const int cc = t & 63;
      Ws[kk][cc] = W[(size_t)(k0 + kk) * Hh + c0 + cc];
    }
    __syncthreads();
    #pragma unroll
    for (int kk = 0; kk < BK; kk++) {
      float a[4], b[4];
      #pragma unroll
      for (int i = 0; i < 4; i++) a[i] = As[kk][ty * 4 + i];
      #pragma unroll
      for (int j = 0; j < 4; j++) b[j] = Ws[kk][tx * 4 + j];
      #pragma unroll
      for (int i = 0; i < 4; i++)
        #pragma unroll
        for (int j = 0; j < 4; j++)
          acc[i][j] = fmaf(a[i], b[j], acc[i][j]);
    }
    __syncthreads();
  }

  #pragma unroll
  for (int i = 0; i < 4; i++) {
    const int row = r0 + ty * 4 + i;
    if (row >= Nn) continue;
    #pragma unroll
    for (int j = 0; j < 4; j++) {
      const int col = c0 + tx * 4 + j;
      float v = acc[i][j] + bias[col];
      if (DOBN)
        v = gamma[col] * (v - mu[col]) * rsqrtf(var[col] + 1e-5f) + beta[col];
      v = LRELU(v);
      C[(size_t)row * Hh + col] = v;
    }
  }
}

// ---------------------------------------------------------------------------
// Pool: segment_sum over sorted batch into pooled[G, 768] at column offset
// ---------------------------------------------------------------------------
__global__ __launch_bounds__(256) void pool_kernel(
    const float* __restrict__ xl, const int* __restrict__ batch,
    float* __restrict__ pooled, int layer)
{
  constexpr int NPB = 16;
  const int n0 = blockIdx.x * NPB;
  const int c  = threadIdx.x;
  if (n0 >= Nn) return;
  float acc = 0.f;
  int curb = batch[n0];
  for (int i = 0; i < NPB; i++) {
    const int n = n0 + i;
    if (n >= Nn) break;
    const int b = batch[n];
    if (b != curb) {
      atomicAdd(pooled + (size_t)curb * 768 + layer * 256 + c, acc);
      acc = 0.f;
      curb = b;
    }
    acc += xl[(size_t)n * 256 + c];
  }
  atomicAdd(pooled + (size_t)curb * 768 + layer * 256 + c, acc);
}

// ---------------------------------------------------------------------------
// MLP head
// ---------------------------------------------------------------------------
__global__ __launch_bounds__(256) void mlp_kernel(
    const float* __restrict__ in, const float* __restrict__ W,
    const float* __restrict__ b, float* __restrict__ out,
    int K, int NC, int act)
{
  const int idx = blockIdx.x * blockDim.x + threadIdx.x;
  if (idx >= Gg * NC) return;
  const int r = idx / NC, c = idx % NC;
  float acc = b[c];
  for (int k = 0; k < K; k++) acc = fmaf(in[r * K + k], W[k * NC + c], acc);
  if (act) { acc = LRELU(acc); acc = LRELU(acc); }
  out[idx] = acc;
}

// ---------------------------------------------------------------------------
extern "C" void kernel_launch(void* const* d_in, const int* in_sizes, int n_in,
                              void* d_out, int out_size, void* d_ws, size_t ws_size,
                              hipStream_t stream)
{
  const float* x     = (const float*)d_in[0];
  const int*   ei    = (const int*)d_in[1];
  const float* ea    = (const float*)d_in[2];
  const int*   batch = (const int*)d_in[3];
  const int* src = ei;
  const int* dst = ei + Ee;

  const float *We[3], *be_[3], *W1[3], *b1[3], *g_[3], *bt_[3], *mu_[3], *var_[3], *W2[3], *b2[3];
  for (int l = 0; l < 3; l++) {
    const int base = 4 + l * 10;
    We[l]  = (const float*)d_in[base + 0];
    be_[l] = (const float*)d_in[base + 1];
    W1[l]  = (const float*)d_in[base + 2];
    b1[l]  = (const float*)d_in[base + 3];
    g_[l]  = (const float*)d_in[base + 4];
    bt_[l] = (const float*)d_in[base + 5];
    mu_[l] = (const float*)d_in[base + 6];
    var_[l]= (const float*)d_in[base + 7];
    W2[l]  = (const float*)d_in[base + 8];
    b2[l]  = (const float*)d_in[base + 9];
  }
  const float *Wm[4], *bm[4];
  for (int i = 0; i < 4; i++) {
    Wm[i] = (const float*)d_in[34 + 2 * i];
    bm[i] = (const float*)d_in[35 + 2 * i];
  }

  // ---- workspace layout ----
  int* deg     = (int*)d_ws;                 // 50000
  int* cursor  = deg + Nn;                   // 50000
  int* row_ptr = cursor + Nn;                // 50001 (+3 pad)
  int* csr_src = row_ptr + Nn + 4;           // 800000
  int* csr_eid = csr_src + Ee;               // 800000
  float* NB0   = (float*)(csr_eid + Ee);     // N*256 each
  float* NB1   = NB0 + (size_t)Nn * Hh;
  float* NB2   = NB1 + (size_t)Nn * Hh;
  float* pooled= NB2 + (size_t)Nn * Hh;      // G*768
  float* h1    = pooled + (size_t)Gg * 768;  // G*200
  float* h2    = h1 + (size_t)Gg * 200;      // G*200
  float* outf  = (float*)d_out;

  const dim3 gemmGrid(Hh / 64, (Nn + 63) / 64);
  const int  poolGrid = (Nn + 15) / 16;
  const int  aggGrid  = (Nn + 3) / 4;
  const int  eGrid    = (Ee + 255) / 256;

  // ---- CSR build (once, reused by all 3 layers) ----
  hipMemsetAsync(deg, 0, Nn * sizeof(int), stream);
  hipMemsetAsync(pooled, 0, (size_t)Gg * 768 * sizeof(float), stream);
  hist_kernel<<<eGrid, 256, 0, stream>>>(dst, deg);
  scan_kernel<<<1, 1024, 0, stream>>>(deg, row_ptr, cursor, Nn);
  fill_kernel<<<eGrid, 256, 0, stream>>>(src, dst, cursor, csr_src, csr_eid);

  // ---- layer 1 (din = 128) ----
  agg_gather<128><<<aggGrid, 256, 0, stream>>>(x, ea, We[0], be_[0], row_ptr, csr_src, csr_eid, NB0);
  node_gemm<128, true, true><<<gemmGrid, 256, 0, stream>>>(
      x, NB0, W1[0], b1[0], g_[0], bt_[0], mu_[0], var_[0], NB1);
  node_gemm<256, false, false><<<gemmGrid, 256, 0, stream>>>(
      NB1, nullptr, W2[0], b2[0], nullptr, nullptr, nullptr, nullptr, NB0);
  pool_kernel<<<poolGrid, 256, 0, stream>>>(NB0, batch, pooled, 0);

  // ---- layer 2 (din = 256) ----
  agg_gather<256><<<aggGrid, 256, 0, stream>>>(NB0, ea, We[1], be_[1], row_ptr, csr_src, csr_eid, NB1);
  node_gemm<256, true, true><<<gemmGrid, 256, 0, stream>>>(
      NB0, NB1, W1[1], b1[1], g_[1], bt_[1], mu_[1], var_[1], NB2);
  node_gemm<256, false, false><<<gemmGrid, 256, 0, stream>>>(
      NB2, nullptr, W2[1], b2[1], nullptr, nullptr, nullptr, nullptr, NB1);
  pool_kernel<<<poolGrid, 256, 0, stream>>>(NB1, batch, pooled, 1);

  // ---- layer 3 (din = 256) ----
  agg_gather<256><<<aggGrid, 256, 0, stream>>>(NB1, ea, We[2], be_[2], row_ptr, csr_src, csr_eid, NB2);
  node_gemm<256, true, true><<<gemmGrid, 256, 0, stream>>>(
      NB1, NB2, W1[2], b1[2], g_[2], bt_[2], mu_[2], var_[2], NB0);
  node_gemm<256, false, false><<<gemmGrid, 256, 0, stream>>>(
      NB0, nullptr, W2[2], b2[2], nullptr, nullptr, nullptr, nullptr, NB2);
  pool_kernel<<<poolGrid, 256, 0, stream>>>(NB2, batch, pooled, 2);

  // ---- MLP head ----
  mlp_kernel<<<(Gg * 200 + 255) / 256, 256, 0, stream>>>(pooled, Wm[0], bm[0], h1, 768, 200, 1);
  mlp_kernel<<<(Gg * 200 + 255) / 256, 256, 0, stream>>>(h1, Wm[1], bm[1], h2, 200, 200, 1);
  mlp_kernel<<<(Gg * 200 + 255) / 256, 256, 0, stream>>>(h2, Wm[2], bm[2], h1, 200, 200, 1);
  mlp_kernel<<<(Gg * Oo + 255) / 256, 256, 0, stream>>>(h1, Wm[3], bm[3], outf, 200, 10, 0);
}

// Round 3
// 900.942 us; speedup vs baseline: 8.9291x; 2.0017x over previous
//
#include <hip/hip_runtime.h>

#define LRELU(v) ((v) >= 0.f ? (v) : 0.2f * (v))
#define DLRELU(v) ((v) >= 0.f ? (v) : 0.04f * (v))

constexpr int Nn = 50000;
constexpr int Ee = 800000;
constexpr int Hh = 256;
constexpr int Gg = 128;
constexpr int Oo = 10;

typedef __attribute__((ext_vector_type(8))) short short8;
typedef __attribute__((ext_vector_type(4))) float f32x4;
typedef __attribute__((ext_vector_type(4))) unsigned short us4;

__device__ inline float bf2f(unsigned short u) {
  union { unsigned int i; float f; } v; v.i = ((unsigned int)u) << 16; return v.f;
}
__device__ inline unsigned short f2bf(float f) {
  union { float f; unsigned int i; } v; v.f = f;
  unsigned int i = v.i;
  return (unsigned short)((i + 0x7FFFu + ((i >> 16) & 1u)) >> 16);
}

// ---------------------------------------------------------------------------
// CSR build
// ---------------------------------------------------------------------------
__global__ __launch_bounds__(256) void hist_kernel(
    const int* __restrict__ dst, int* __restrict__ deg)
{
  const int e = blockIdx.x * 256 + threadIdx.x;
  if (e < Ee) atomicAdd(&deg[dst[e]], 1);
}

__global__ __launch_bounds__(1024) void scan_kernel(
    const int* __restrict__ deg, int* __restrict__ row_ptr,
    int* __restrict__ cursor, int n)
{
  __shared__ int sdata[1024];
  __shared__ int carry;
  const int tid = threadIdx.x;
  if (tid == 0) carry = 0;
  __syncthreads();
  for (int base = 0; base < n; base += 1024) {
    const int i = base + tid;
    const int v = (i < n) ? deg[i] : 0;
    sdata[tid] = v;
    __syncthreads();
    #pragma unroll
    for (int off = 1; off < 1024; off <<= 1) {
      const int t = (tid >= off) ? sdata[tid - off] : 0;
      __syncthreads();
      sdata[tid] += t;
      __syncthreads();
    }
    const int excl = sdata[tid] - v + carry;
    if (i < n) { row_ptr[i] = excl; cursor[i] = excl; }
    __syncthreads();
    if (tid == 1023) carry += sdata[1023];
    __syncthreads();
  }
  if (tid == 0) row_ptr[n] = carry;
}

// fill: also permute edge_attr into CSR order (eaP), drop csr_eid
__global__ __launch_bounds__(256) void fill_kernel(
    const int* __restrict__ src, const int* __restrict__ dst,
    const float* __restrict__ ea, int* __restrict__ cursor,
    int* __restrict__ csr_src, float* __restrict__ eaP)
{
  const int e = blockIdx.x * 256 + threadIdx.x;
  if (e >= Ee) return;
  const int pos = atomicAdd(&cursor[dst[e]], 1);
  csr_src[pos] = src[e];
  eaP[3 * pos + 0] = ea[3 * e + 0];
  eaP[3 * pos + 1] = ea[3 * e + 1];
  eaP[3 * pos + 2] = ea[3 * e + 2];
}

// ---------------------------------------------------------------------------
// Converters
// ---------------------------------------------------------------------------
__global__ __launch_bounds__(256) void f2bf_kernel(
    const float* __restrict__ in, unsigned short* __restrict__ out, int n4)
{
  const int i = blockIdx.x * 256 + threadIdx.x;
  if (i >= n4) return;
  const float4 v = *reinterpret_cast<const float4*>(in + (size_t)i * 4);
  us4 o; o.x = f2bf(v.x); o.y = f2bf(v.y); o.z = f2bf(v.z); o.w = f2bf(v.w);
  *reinterpret_cast<us4*>(out + (size_t)i * 4) = o;
}

// W [K,256] fp32 -> Bt [256,K] bf16 (transpose+convert)
__global__ __launch_bounds__(256) void wt_kernel(
    const float* __restrict__ W, unsigned short* __restrict__ Bt, int K)
{
  const int g = blockIdx.x * 256 + threadIdx.x;
  if (g >= 256 * K) return;
  const int c = g & 255, k = g >> 8;
  Bt[(size_t)c * K + k] = f2bf(W[(size_t)k * 256 + c]);
}

// ---------------------------------------------------------------------------
// Gather aggregation (bf16 features): S[n] = bf16( x[n] + sum_e ReLU(x[src]+ea@We+be) )
// one wave per node
// ---------------------------------------------------------------------------
template<int DIN>
__global__ __launch_bounds__(256) void agg_gather(
    const unsigned short* __restrict__ x, const float* __restrict__ eaP,
    const float* __restrict__ We, const float* __restrict__ be,
    const int* __restrict__ row_ptr, const int* __restrict__ csr_src,
    unsigned short* __restrict__ S)
{
  constexpr int FPL = DIN / 64;  // 2 (DIN=128) or 4 (DIN=256)
  const int wv   = threadIdx.x >> 6;
  const int lane = threadIdx.x & 63;
  const int n = blockIdx.x * 4 + wv;
  if (n >= Nn) return;
  const int fo = lane * FPL;

  float w0[FPL], w1[FPL], w2[FPL], bb[FPL], acc[FPL];
  #pragma unroll
  for (int j = 0; j < FPL; j++) {
    w0[j] = We[0 * DIN + fo + j];
    w1[j] = We[1 * DIN + fo + j];
    w2[j] = We[2 * DIN + fo + j];
    bb[j] = be[fo + j];
    acc[j] = 0.f;
  }

  const int beg = row_ptr[n], end = row_ptr[n + 1];
  for (int i = beg; i < end; i++) {
    const int s = csr_src[i];
    const float a0 = eaP[3 * i + 0], a1 = eaP[3 * i + 1], a2 = eaP[3 * i + 2];
    float xv[FPL];
    if constexpr (FPL == 4) {
      const us4 v = *reinterpret_cast<const us4*>(x + (size_t)s * DIN + fo);
      xv[0] = bf2f(v.x); xv[1] = bf2f(v.y); xv[2] = bf2f(v.z); xv[3] = bf2f(v.w);
    } else {
      const unsigned int u = *reinterpret_cast<const unsigned int*>(x + (size_t)s * DIN + fo);
      xv[0] = bf2f((unsigned short)(u & 0xFFFF));
      xv[1] = bf2f((unsigned short)(u >> 16));
    }
    #pragma unroll
    for (int j = 0; j < FPL; j++) {
      const float m = xv[j] + a0 * w0[j] + a1 * w1[j] + a2 * w2[j] + bb[j];
      acc[j] += fmaxf(m, 0.f);
    }
  }

  // add own node features and emit bf16
  unsigned short o[FPL];
  if constexpr (FPL == 4) {
    const us4 v = *reinterpret_cast<const us4*>(x + (size_t)n * DIN + fo);
    o[0] = f2bf(bf2f(v.x) + acc[0]); o[1] = f2bf(bf2f(v.y) + acc[1]);
    o[2] = f2bf(bf2f(v.z) + acc[2]); o[3] = f2bf(bf2f(v.w) + acc[3]);
    us4 ov; ov.x = o[0]; ov.y = o[1]; ov.z = o[2]; ov.w = o[3];
    *reinterpret_cast<us4*>(S + (size_t)n * DIN + fo) = ov;
  } else {
    const unsigned int u = *reinterpret_cast<const unsigned int*>(x + (size_t)n * DIN + fo);
    o[0] = f2bf(bf2f((unsigned short)(u & 0xFFFF)) + acc[0]);
    o[1] = f2bf(bf2f((unsigned short)(u >> 16)) + acc[1]);
    *reinterpret_cast<unsigned int*>(S + (size_t)n * DIN + fo) =
        (unsigned int)o[0] | ((unsigned int)o[1] << 16);
  }
}

// ---------------------------------------------------------------------------
// MFMA GEMM: C[N,256] = epi( A[N,K]bf16 @ W[K,256] ), Bt = W^T bf16 [256,K]
// block tile 128x64, 4 waves (2x2), wave tile 64x32, 16x16x32 MFMA
// ---------------------------------------------------------------------------
template<int K, bool DOBN>
__global__ __launch_bounds__(256) void gemm_mfma(
    const unsigned short* __restrict__ A, const unsigned short* __restrict__ Bt,
    const float* __restrict__ bias,
    const float* __restrict__ gamma, const float* __restrict__ beta,
    const float* __restrict__ mu, const float* __restrict__ var,
    unsigned short* __restrict__ C)
{
  __shared__ __align__(16) unsigned short lA[128 * 40];  // 80B row stride
  const int t = threadIdx.x;
  const int lane = t & 63;
  const int wid = t >> 6;
  const int wrow = wid >> 1, wcol = wid & 1;
  const int n0 = blockIdx.y * 128;
  const int c0 = blockIdx.x * 64;
  const int l15 = lane & 15, hi = lane >> 4;
  const int colA = c0 + wcol * 32 + l15;

  f32x4 acc[4][2] = {};

  for (int k0 = 0; k0 < K; k0 += 32) {
    // stage A tile [128][32] bf16
    #pragma unroll
    for (int i = 0; i < 2; i++) {
      const int chunk = i * 256 + t;
      const int r = chunk >> 2, q = chunk & 3;
      const int gr = n0 + r;
      short8 v = {0, 0, 0, 0, 0, 0, 0, 0};
      if (gr < Nn)
        v = *reinterpret_cast<const short8*>(&A[(size_t)gr * K + k0 + q * 8]);
      *reinterpret_cast<short8*>(&lA[r * 40 + q * 8]) = v;
    }
    __syncthreads();
    short8 bfr[2];
    #pragma unroll
    for (int cf = 0; cf < 2; cf++)
      bfr[cf] = *reinterpret_cast<const short8*>(
          &Bt[(size_t)(colA + cf * 16) * K + k0 + hi * 8]);
    #pragma unroll
    for (int rf = 0; rf < 4; rf++) {
      const short8 av = *reinterpret_cast<const short8*>(
          &lA[(wrow * 64 + rf * 16 + l15) * 40 + hi * 8]);
      acc[rf][0] = __builtin_amdgcn_mfma_f32_16x16x32_bf16(av, bfr[0], acc[rf][0], 0, 0, 0);
      acc[rf][1] = __builtin_amdgcn_mfma_f32_16x16x32_bf16(av, bfr[1], acc[rf][1], 0, 0, 0);
    }
    __syncthreads();
  }

  #pragma unroll
  for (int cf = 0; cf < 2; cf++) {
    const int col = colA + cf * 16;
    const float bs = bias[col];
    #pragma unroll
    for (int rf = 0; rf < 4; rf++) {
      #pragma unroll
      for (int rg = 0; rg < 4; rg++) {
        const int row = n0 + wrow * 64 + rf * 16 + hi * 4 + rg;
        if (row >= Nn) continue;
        float v = acc[rf][cf][rg] + bs;
        if constexpr (DOBN)
          v = gamma[col] * (v - mu[col]) * rsqrtf(var[col] + 1e-5f) + beta[col];
        v = LRELU(v);
        C[(size_t)row * 256 + col] = f2bf(v);
      }
    }
  }
}

// ---------------------------------------------------------------------------
// Pool: segment_sum (sorted batch) of bf16 features into pooled[G,768] fp32
// ---------------------------------------------------------------------------
__global__ __launch_bounds__(256) void pool_kernel(
    const unsigned short* __restrict__ xl, const int* __restrict__ batch,
    float* __restrict__ pooled, int layer)
{
  constexpr int NPB = 16;
  const int n0 = blockIdx.x * NPB;
  const int c  = threadIdx.x;
  if (n0 >= Nn) return;
  float acc = 0.f;
  int curb = batch[n0];
  for (int i = 0; i < NPB; i++) {
    const int n = n0 + i;
    if (n >= Nn) break;
    const int b = batch[n];
    if (b != curb) {
      atomicAdd(pooled + (size_t)curb * 768 + layer * 256 + c, acc);
      acc = 0.f;
      curb = b;
    }
    acc += bf2f(xl[(size_t)n * 256 + c]);
  }
  atomicAdd(pooled + (size_t)curb * 768 + layer * 256 + c, acc);
}

// ---------------------------------------------------------------------------
// Fused MLP head: one block per graph row, activations in LDS
// ---------------------------------------------------------------------------
__global__ __launch_bounds__(256) void mlp_fused(
    const float* __restrict__ pooled,
    const float* __restrict__ W1, const float* __restrict__ b1,
    const float* __restrict__ W2, const float* __restrict__ b2,
    const float* __restrict__ W3, const float* __restrict__ b3,
    const float* __restrict__ W4, const float* __restrict__ b4,
    float* __restrict__ out)
{
  __shared__ float buf[768];
  __shared__ float h[200];
  const int g = blockIdx.x, t = threadIdx.x;
  for (int i = t; i < 768; i += 256) buf[i] = pooled[(size_t)g * 768 + i];
  __syncthreads();
  if (t < 200) {
    float a = b1[t];
    #pragma unroll 4
    for (int k = 0; k < 768; k++) a = fmaf(buf[k], W1[k * 200 + t], a);
    h[t] = DLRELU(a);
  }
  __syncthreads();
  if (t < 200) buf[t] = h[t];
  __syncthreads();
  if (t < 200) {
    float a = b2[t];
    #pragma unroll 4
    for (int k = 0; k < 200; k++) a = fmaf(buf[k], W2[k * 200 + t], a);
    h[t] = DLRELU(a);
  }
  __syncthreads();
  if (t < 200) buf[t] = h[t];
  __syncthreads();
  if (t < 200) {
    float a = b3[t];
    #pragma unroll 4
    for (int k = 0; k < 200; k++) a = fmaf(buf[k], W3[k * 200 + t], a);
    h[t] = DLRELU(a);
  }
  __syncthreads();
  if (t < 200) buf[t] = h[t];
  __syncthreads();
  if (t < Oo) {
    float a = b4[t];
    #pragma unroll 4
    for (int k = 0; k < 200; k++) a = fmaf(buf[k], W4[k * Oo + t], a);
    out[(size_t)g * Oo + t] = a;
  }
}

// ---------------------------------------------------------------------------
extern "C" void kernel_launch(void* const* d_in, const int* in_sizes, int n_in,
                              void* d_out, int out_size, void* d_ws, size_t ws_size,
                              hipStream_t stream)
{
  const float* x     = (const float*)d_in[0];
  const int*   ei    = (const int*)d_in[1];
  const float* ea    = (const float*)d_in[2];
  const int*   batch = (const int*)d_in[3];
  const int* src = ei;
  const int* dst = ei + Ee;

  const float *We[3], *be_[3], *W1[3], *b1[3], *g_[3], *bt_[3], *mu_[3], *var_[3], *W2[3], *b2[3];
  for (int l = 0; l < 3; l++) {
    const int base = 4 + l * 10;
    We[l]  = (const float*)d_in[base + 0];
    be_[l] = (const float*)d_in[base + 1];
    W1[l]  = (const float*)d_in[base + 2];
    b1[l]  = (const float*)d_in[base + 3];
    g_[l]  = (const float*)d_in[base + 4];
    bt_[l] = (const float*)d_in[base + 5];
    mu_[l] = (const float*)d_in[base + 6];
    var_[l]= (const float*)d_in[base + 7];
    W2[l]  = (const float*)d_in[base + 8];
    b2[l]  = (const float*)d_in[base + 9];
  }
  const float *Wm[4], *bm[4];
  for (int i = 0; i < 4; i++) {
    Wm[i] = (const float*)d_in[34 + 2 * i];
    bm[i] = (const float*)d_in[35 + 2 * i];
  }

  // ---- workspace layout ----
  int* deg     = (int*)d_ws;                        // Nn
  int* cursor  = deg + Nn;                          // Nn
  int* row_ptr = cursor + Nn;                       // Nn+4
  int* csr_src = row_ptr + Nn + 4;                  // Ee
  float* eaP   = (float*)(csr_src + Ee);            // 3*Ee
  unsigned short* x0bf = (unsigned short*)(eaP + (size_t)3 * Ee);  // Nn*128
  unsigned short* Wt   = x0bf + (size_t)Nn * 128;   // 32768 + 5*65536
  unsigned short* Wt11 = Wt;                        // 256x128
  unsigned short* Wt12 = Wt11 + 32768;              // 256x256
  unsigned short* Wt21 = Wt12 + 65536;
  unsigned short* Wt22 = Wt21 + 65536;
  unsigned short* Wt31 = Wt22 + 65536;
  unsigned short* Wt32 = Wt31 + 65536;
  unsigned short* S    = Wt32 + 65536;              // Nn*256
  unsigned short* Y    = S  + (size_t)Nn * Hh;      // Nn*256
  unsigned short* XB0  = Y  + (size_t)Nn * Hh;      // Nn*256
  unsigned short* XB1  = XB0 + (size_t)Nn * Hh;     // Nn*256
  float* pooled = (float*)(XB1 + (size_t)Nn * Hh);  // Gg*768
  float* outf   = (float*)d_out;

  const dim3 gemmGrid(Hh / 64, (Nn + 127) / 128);
  const int  poolGrid = (Nn + 15) / 16;
  const int  aggGrid  = (Nn + 3) / 4;
  const int  eGrid    = (Ee + 255) / 256;

  hipMemsetAsync(deg, 0, Nn * sizeof(int), stream);
  hipMemsetAsync(pooled, 0, (size_t)Gg * 768 * sizeof(float), stream);

  // CSR build (once)
  hist_kernel<<<eGrid, 256, 0, stream>>>(dst, deg);
  scan_kernel<<<1, 1024, 0, stream>>>(deg, row_ptr, cursor, Nn);
  fill_kernel<<<eGrid, 256, 0, stream>>>(src, dst, ea, cursor, csr_src, eaP);

  // converts
  f2bf_kernel<<<(Nn * 128 / 4 + 255) / 256, 256, 0, stream>>>(x, x0bf, Nn * 128 / 4);
  wt_kernel<<<(256 * 128 + 255) / 256, 256, 0, stream>>>(W1[0], Wt11, 128);
  wt_kernel<<<(256 * 256 + 255) / 256, 256, 0, stream>>>(W2[0], Wt12, 256);
  wt_kernel<<<(256 * 256 + 255) / 256, 256, 0, stream>>>(W1[1], Wt21, 256);
  wt_kernel<<<(256 * 256 + 255) / 256, 256, 0, stream>>>(W2[1], Wt22, 256);
  wt_kernel<<<(256 * 256 + 255) / 256, 256, 0, stream>>>(W1[2], Wt31, 256);
  wt_kernel<<<(256 * 256 + 255) / 256, 256, 0, stream>>>(W2[2], Wt32, 256);

  // ---- layer 1 (din = 128) ----
  agg_gather<128><<<aggGrid, 256, 0, stream>>>(x0bf, eaP, We[0], be_[0], row_ptr, csr_src, S);
  gemm_mfma<128, true><<<gemmGrid, 256, 0, stream>>>(
      S, Wt11, b1[0], g_[0], bt_[0], mu_[0], var_[0], Y);
  gemm_mfma<256, false><<<gemmGrid, 256, 0, stream>>>(
      Y, Wt12, b2[0], nullptr, nullptr, nullptr, nullptr, XB0);
  pool_kernel<<<poolGrid, 256, 0, stream>>>(XB0, batch, pooled, 0);

  // ---- layer 2 (din = 256) ----
  agg_gather<256><<<aggGrid, 256, 0, stream>>>(XB0, eaP, We[1], be_[1], row_ptr, csr_src, S);
  gemm_mfma<256, true><<<gemmGrid, 256, 0, stream>>>(
      S, Wt21, b1[1], g_[1], bt_[1], mu_[1], var_[1], Y);
  gemm_mfma<256, false><<<gemmGrid, 256, 0, stream>>>(
      Y, Wt22, b2[1], nullptr, nullptr, nullptr, nullptr, XB1);
  pool_kernel<<<poolGrid, 256, 0, stream>>>(XB1, batch, pooled, 1);

  // ---- layer 3 (din = 256) ----
  agg_gather<256><<<aggGrid, 256, 0, stream>>>(XB1, eaP, We[2], be_[2], row_ptr, csr_src, S);
  gemm_mfma<256, true><<<gemmGrid, 256, 0, stream>>>(
      S, Wt31, b1[2], g_[2], bt_[2], mu_[2], var_[2], Y);
  gemm_mfma<256, false><<<gemmGrid, 256, 0, stream>>>(
      Y, Wt32, b2[2], nullptr, nullptr, nullptr, nullptr, XB0);
  pool_kernel<<<poolGrid, 256, 0, stream>>>(XB0, batch, pooled, 2);

  // ---- fused MLP head ----
  mlp_fused<<<Gg, 256, 0, stream>>>(pooled, Wm[0], bm[0], Wm[1], bm[1],
                                    Wm[2], bm[2], Wm[3], bm[3], outf);
}